// Round 2
// baseline (908.080 us; speedup 1.0000x reference)
//
#include <hip/hip_runtime.h>
#include <math.h>

typedef _Float16 half8  __attribute__((ext_vector_type(8)));
typedef _Float16 half4v __attribute__((ext_vector_type(4)));
typedef __fp16   fp16x2 __attribute__((ext_vector_type(2)));
typedef float    f32x16 __attribute__((ext_vector_type(16)));

namespace {
constexpr int H      = 4096;
constexpr int E      = 256;
constexpr int TOPK   = 8;
constexpr int NCAND  = 12;           // screened candidates per token
constexpr int BM     = 64;           // tokens per block (main kernel)
constexpr int BK     = 32;           // k per chunk
constexpr int NCHUNK = H / BK;       // 128
constexpr int SLD    = E + 4;        // 260, score row stride (floats)
constexpr float DELTA = 5e-4f;       // near-tie rescue threshold (logit units)
constexpr size_t WF_BYTES = (size_t)E * H * 2 * 2;  // 4 MB: hi+lo fp16
}

// ---------------- W pre-convert: fp32 -> fragment-ordered hi/lo fp16 --------
// Layout (halves): [nt(8)][ks(256)][hilo(2)][lane(64)][j(8)]
//   element W[e][k] (scaled by 64): nt=e>>5, ks=k>>4,
//   lane=(e&31) | (((k>>3)&1)<<5), j=k&7
__global__ void convert_w_kernel(const float* __restrict__ W,
                                 _Float16* __restrict__ Wf) {
    int t  = blockIdx.x * blockDim.x + threadIdx.x;
    int e  = t >> 10;
    int kq = t & 1023;           // k = kq*4
    float4 w4 = *(const float4*)(W + ((size_t)e << 12) + (kq << 2));
    float x0 = w4.x * 64.0f, x1 = w4.y * 64.0f, x2 = w4.z * 64.0f, x3 = w4.w * 64.0f;
    _Float16 h0 = (_Float16)x0, h1 = (_Float16)x1, h2 = (_Float16)x2, h3 = (_Float16)x3;
    _Float16 l0 = (_Float16)(x0 - (float)h0), l1 = (_Float16)(x1 - (float)h1);
    _Float16 l2 = (_Float16)(x2 - (float)h2), l3 = (_Float16)(x3 - (float)h3);
    int k    = kq << 2;
    int nt   = e >> 5;
    int ks   = k >> 4;
    int lane = (e & 31) | (((k >> 3) & 1) << 5);
    int j    = k & 7;            // 0 or 4
    size_t base = (((size_t)nt * 256 + ks) * 2) * 512 + lane * 8 + j;
    half4v hv = {h0, h1, h2, h3};
    half4v lv = {l0, l1, l2, l3};
    *(half4v*)(Wf + base)       = hv;   // hilo=0
    *(half4v*)(Wf + base + 512) = lv;   // hilo=1
}

// ---------------- main fused kernel: barrier-free split-fp16 MFMA + top8 ----
// 16 waves: mt (row half, 0..1) x wc (32-expert slice, 0..7).
// A fragments loaded DIRECTLY from global X (no LDS staging, no K-loop
// barriers), converted to hi/lo fp16 in registers. Register double-buffer
// (depth-1 prefetch); compiler emits counted vmcnt instead of full drains.
struct Pipe { half8 bh[2], bl[2]; float4 a[2][2]; };

__global__ __launch_bounds__(1024, 4)
void moe_gate_mfma(const float* __restrict__ X, const _Float16* __restrict__ Wf,
                   const float* __restrict__ Wg,
                   float* __restrict__ out_idx, float* __restrict__ out_w) {
    __shared__ float sc[BM * SLD];   // epilogue scores only (66560 B)

    const int tid  = threadIdx.x;
    const int lane = tid & 63;
    const int wave = tid >> 6;      // 0..15
    const int mt   = wave >> 3;     // row half (0..1)
    const int wc   = wave & 7;      // expert slice (0..7), 32 experts each
    const int m0   = blockIdx.x * BM;

    // A-fragment addressing for mfma_32x32x16_f16:
    //   lane holds A[row = lane&31][k = ks*16 + (lane>>5)*8 + (0..7)]
    const int arow = lane & 31;
    const int akhi = (lane >> 5) << 3;     // 0 or 8
    const float* xrow = X + (size_t)(m0 + mt * 32 + arow) * H + akhi;
    const _Float16* wbase = Wf + (size_t)wc * 256 * 2 * 512 + (size_t)lane * 8;

    f32x16 acc;
    #pragma unroll
    for (int r = 0; r < 16; ++r) acc[r] = 0.0f;

    auto load_pipe = [&](int kc, Pipe& P) {
        #pragma unroll
        for (int ks = 0; ks < 2; ++ks) {
            size_t off = (size_t)(kc * 2 + ks) * 1024;
            P.bh[ks]   = *(const half8*)(wbase + off);
            P.bl[ks]   = *(const half8*)(wbase + off + 512);
            P.a[ks][0] = *(const float4*)(xrow + kc * 32 + ks * 16);
            P.a[ks][1] = *(const float4*)(xrow + kc * 32 + ks * 16 + 4);
        }
    };
    auto compute = [&](const Pipe& P) {
        #pragma unroll
        for (int ks = 0; ks < 2; ++ks) {
            const float4 u = P.a[ks][0], v = P.a[ks][1];
            fp16x2 h0 = __builtin_amdgcn_cvt_pkrtz(u.x, u.y);
            fp16x2 h1 = __builtin_amdgcn_cvt_pkrtz(u.z, u.w);
            fp16x2 h2 = __builtin_amdgcn_cvt_pkrtz(v.x, v.y);
            fp16x2 h3 = __builtin_amdgcn_cvt_pkrtz(v.z, v.w);
            fp16x2 l0 = __builtin_amdgcn_cvt_pkrtz(u.x - (float)h0.x, u.y - (float)h0.y);
            fp16x2 l1 = __builtin_amdgcn_cvt_pkrtz(u.z - (float)h1.x, u.w - (float)h1.y);
            fp16x2 l2 = __builtin_amdgcn_cvt_pkrtz(v.x - (float)h2.x, v.y - (float)h2.y);
            fp16x2 l3 = __builtin_amdgcn_cvt_pkrtz(v.z - (float)h3.x, v.w - (float)h3.y);
            half8 ah = {(_Float16)h0.x, (_Float16)h0.y, (_Float16)h1.x, (_Float16)h1.y,
                        (_Float16)h2.x, (_Float16)h2.y, (_Float16)h3.x, (_Float16)h3.y};
            half8 al = {(_Float16)l0.x, (_Float16)l0.y, (_Float16)l1.x, (_Float16)l1.y,
                        (_Float16)l2.x, (_Float16)l2.y, (_Float16)l3.x, (_Float16)l3.y};
            acc = __builtin_amdgcn_mfma_f32_32x32x16_f16(ah, P.bh[ks], acc, 0, 0, 0);
            acc = __builtin_amdgcn_mfma_f32_32x32x16_f16(al, P.bh[ks], acc, 0, 0, 0);
            acc = __builtin_amdgcn_mfma_f32_32x32x16_f16(ah, P.bl[ks], acc, 0, 0, 0);
        }
    };

    Pipe p0, p1;
    load_pipe(0, p0);
    #pragma unroll 1
    for (int kc = 0; kc < NCHUNK; kc += 2) {
        const int k1 = kc + 1;                                // always < NCHUNK
        const int k2 = (kc + 2 < NCHUNK) ? kc + 2 : kc;       // tail-safe dup
        load_pipe(k1, p1);
        compute(p0);
        load_pipe(k2, p0);
        compute(p1);
    }

    // -------- logits -> LDS (undo the x64 W prescale) --------
    #pragma unroll
    for (int r = 0; r < 16; ++r) {
        int row = (r & 3) + 8 * (r >> 2) + 4 * (lane >> 5);
        int col = lane & 31;
        sc[(mt * 32 + row) * SLD + wc * 32 + col] = acc[r] * 0.015625f;
    }
    __syncthreads();

    // -------- top-12 screen on logits + fp64 rescue for near-ties -----------
    for (int t4 = 0; t4 < 4; ++t4) {
        const int t = wave * 4 + t4;
        float4 pv = *(const float4*)(sc + t * SLD + lane * 4);
        float p0s = pv.x, p1s = pv.y, p2s = pv.z, p3s = pv.w;

        float tv[NCAND]; int ti[NCAND];
        #pragma unroll
        for (int s = 0; s < NCAND; ++s) {
            float bv = p0s; int bi = lane * 4;
            if (p1s > bv || (p1s == bv && lane * 4 + 1 < bi)) { bv = p1s; bi = lane * 4 + 1; }
            if (p2s > bv || (p2s == bv && lane * 4 + 2 < bi)) { bv = p2s; bi = lane * 4 + 2; }
            if (p3s > bv || (p3s == bv && lane * 4 + 3 < bi)) { bv = p3s; bi = lane * 4 + 3; }
            #pragma unroll
            for (int off = 32; off > 0; off >>= 1) {
                float ov = __shfl_xor(bv, off, 64);
                int   oi = __shfl_xor(bi, off, 64);
                if (ov > bv || (ov == bv && oi < bi)) { bv = ov; bi = oi; }
            }
            tv[s] = bv; ti[s] = bi;
            if ((bi >> 2) == lane) {
                const int sl = bi & 3;
                if      (sl == 0) p0s = -3e38f;
                else if (sl == 1) p1s = -3e38f;
                else if (sl == 2) p2s = -3e38f;
                else              p3s = -3e38f;
            }
        }

        // near-tie detection among the decisive gaps (ranks 0-1 .. 8-9)
        bool rescue = false;
        #pragma unroll
        for (int g = 0; g < 9; ++g) rescue |= (tv[g] - tv[g + 1] < DELTA);

        if (rescue) {  // wave-uniform branch (tv identical across lanes)
            double dv[NCAND];
            const float* xr = X + (size_t)(m0 + t) * H;
            #pragma unroll 1
            for (int c = 0; c < NCAND; ++c) {
                const float* wrow = Wg + (size_t)ti[c] * H;
                double s_ = 0.0;
                #pragma unroll
                for (int it = 0; it < 16; ++it) {
                    float4 xa = *(const float4*)(xr + it * 256 + lane * 4);
                    float4 wa = *(const float4*)(wrow + it * 256 + lane * 4);
                    s_ += (double)xa.x * wa.x + (double)xa.y * wa.y
                        + (double)xa.z * wa.z + (double)xa.w * wa.w;
                }
                #pragma unroll
                for (int off = 32; off > 0; off >>= 1) s_ += __shfl_xor(s_, off, 64);
                dv[c] = s_;
            }
            // exact selection sort of top 8 (desc, lower index on tie)
            int si[NCAND];
            #pragma unroll
            for (int c = 0; c < NCAND; ++c) si[c] = ti[c];
            #pragma unroll
            for (int a = 0; a < TOPK; ++a) {
                int best = a;
                #pragma unroll
                for (int b = a + 1; b < NCAND; ++b) {
                    if (dv[b] > dv[best] || (dv[b] == dv[best] && si[b] < si[best])) best = b;
                }
                double tdv = dv[a]; dv[a] = dv[best]; dv[best] = tdv;
                int    tsi = si[a]; si[a] = si[best]; si[best] = tsi;
            }
            #pragma unroll
            for (int s = 0; s < TOPK; ++s) { tv[s] = (float)dv[s]; ti[s] = si[s]; }
        }

        if (lane == 0) {
            // weights = 2.5 * softmax over the top-8 logits (full-Z cancels)
            float M = tv[0];
            float e8[TOPK]; float den = 0.0f;
            #pragma unroll
            for (int s = 0; s < TOPK; ++s) { e8[s] = expf(tv[s] - M); den += e8[s]; }
            float scl = 2.5f / den;
            size_t tok = (size_t)(m0 + t);
            #pragma unroll
            for (int s = 0; s < TOPK; ++s) {
                out_idx[tok * TOPK + s] = (float)ti[s];
                out_w[tok * TOPK + s]   = e8[s] * scl;
            }
        }
    }
}

// ---------------- fallback (round-1 fp32 kernel, correctness-proven) --------
namespace fb {
constexpr int BM = 32, BK = 32;
constexpr int XS_LD = BM + 4, WS_LD = E + 4;
constexpr int LDS_FLOATS = BK * XS_LD + BK * WS_LD;
}

__global__ __launch_bounds__(256, 2)
void moe_gate_fallback(const float* __restrict__ X, const float* __restrict__ W,
                       float* __restrict__ out_idx, float* __restrict__ out_w) {
    __shared__ float lds[fb::LDS_FLOATS];
    float* xs = lds;
    float* ws = lds + fb::BK * fb::XS_LD;
    const int tid = threadIdx.x;
    const int tx = tid & 31, ty = tid >> 5;
    const int m0 = blockIdx.x * fb::BM;
    float acc[4][8];
    #pragma unroll
    for (int i = 0; i < 4; ++i)
        #pragma unroll
        for (int j = 0; j < 8; ++j) acc[i][j] = 0.0f;
    const int lr = tid >> 3, lc = (tid & 7) * 4;
    const float* xg = X + (size_t)(m0 + lr) * H + lc;
    const float* wg = W + (size_t)lr * H + lc;
    for (int kc = 0; kc < H; kc += fb::BK) {
        float4 xv = *(const float4*)(xg + kc);
        float4 wv[8];
        #pragma unroll
        for (int i = 0; i < 8; ++i) wv[i] = *(const float4*)(wg + (size_t)i * 32 * H + kc);
        __syncthreads();
        #pragma unroll
        for (int j = 0; j < 4; ++j) xs[(lc + j) * fb::XS_LD + lr] = ((const float*)&xv)[j];
        #pragma unroll
        for (int i = 0; i < 8; ++i)
            #pragma unroll
            for (int j = 0; j < 4; ++j)
                ws[(lc + j) * fb::WS_LD + i * 32 + lr] = ((const float*)&wv[i])[j];
        __syncthreads();
        #pragma unroll
        for (int kk = 0; kk < fb::BK; ++kk) {
            float4 xa = *(const float4*)(xs + kk * fb::XS_LD + ty * 4);
            float4 wb0 = *(const float4*)(ws + kk * fb::WS_LD + tx * 8);
            float4 wb1 = *(const float4*)(ws + kk * fb::WS_LD + tx * 8 + 4);
            const float xr[4] = {xa.x, xa.y, xa.z, xa.w};
            const float wr8[8] = {wb0.x, wb0.y, wb0.z, wb0.w, wb1.x, wb1.y, wb1.z, wb1.w};
            #pragma unroll
            for (int i = 0; i < 4; ++i)
                #pragma unroll
                for (int j = 0; j < 8; ++j) acc[i][j] = fmaf(xr[i], wr8[j], acc[i][j]);
        }
    }
    __syncthreads();
    float* sc = lds;
    #pragma unroll
    for (int i = 0; i < 4; ++i) {
        *(float4*)(sc + (ty * 4 + i) * fb::WS_LD + tx * 8) =
            make_float4(acc[i][0], acc[i][1], acc[i][2], acc[i][3]);
        *(float4*)(sc + (ty * 4 + i) * fb::WS_LD + tx * 8 + 4) =
            make_float4(acc[i][4], acc[i][5], acc[i][6], acc[i][7]);
    }
    __syncthreads();
    const int wave = tid >> 6, lane = tid & 63;
    for (int t8 = 0; t8 < 8; ++t8) {
        const int t = wave * 8 + t8;
        float4 pv = *(const float4*)(sc + t * fb::WS_LD + lane * 4);
        float v0 = pv.x, v1 = pv.y, v2 = pv.z, v3 = pv.w;
        float M = fmaxf(fmaxf(v0, v1), fmaxf(v2, v3));
        #pragma unroll
        for (int off = 32; off > 0; off >>= 1) M = fmaxf(M, __shfl_xor(M, off, 64));
        float p0 = expf(v0 - M), p1 = expf(v1 - M), p2 = expf(v2 - M), p3 = expf(v3 - M);
        float z = p0 + p1 + p2 + p3;
        #pragma unroll
        for (int off = 32; off > 0; off >>= 1) z += __shfl_xor(z, off, 64);
        p0 /= z; p1 /= z; p2 /= z; p3 /= z;
        float tv[TOPK]; int ti[TOPK];
        #pragma unroll
        for (int s = 0; s < TOPK; ++s) {
            float bv = p0; int bi = lane * 4;
            if (p1 > bv || (p1 == bv && lane * 4 + 1 < bi)) { bv = p1; bi = lane * 4 + 1; }
            if (p2 > bv || (p2 == bv && lane * 4 + 2 < bi)) { bv = p2; bi = lane * 4 + 2; }
            if (p3 > bv || (p3 == bv && lane * 4 + 3 < bi)) { bv = p3; bi = lane * 4 + 3; }
            #pragma unroll
            for (int off = 32; off > 0; off >>= 1) {
                float ov = __shfl_xor(bv, off, 64);
                int   oi = __shfl_xor(bi, off, 64);
                if (ov > bv || (ov == bv && oi < bi)) { bv = ov; bi = oi; }
            }
            tv[s] = bv; ti[s] = bi;
            if ((bi >> 2) == lane) {
                const int sl = bi & 3;
                if      (sl == 0) p0 = -1.0f;
                else if (sl == 1) p1 = -1.0f;
                else if (sl == 2) p2 = -1.0f;
                else              p3 = -1.0f;
            }
        }
        if (lane == 0) {
            float den = tv[0] + tv[1] + tv[2] + tv[3] + tv[4] + tv[5] + tv[6] + tv[7] + 1e-20f;
            float scl = 2.5f / den;
            size_t tok = (size_t)(m0 + t);
            #pragma unroll
            for (int s = 0; s < TOPK; ++s) {
                out_idx[tok * TOPK + s] = (float)ti[s];
                out_w[tok * TOPK + s]   = tv[s] * scl;
            }
        }
    }
}

extern "C" void kernel_launch(void* const* d_in, const int* in_sizes, int n_in,
                              void* d_out, int out_size, void* d_ws, size_t ws_size,
                              hipStream_t stream) {
    const float* X = (const float*)d_in[0];
    const float* W = (const float*)d_in[1];
    float* out = (float*)d_out;
    const int T = in_sizes[0] / H;
    float* out_idx = out;
    float* out_w   = out + (size_t)T * TOPK;

    if (ws_size >= WF_BYTES && (T % BM) == 0) {
        _Float16* Wf = (_Float16*)d_ws;
        hipLaunchKernelGGL(convert_w_kernel, dim3((E * (H / 4)) / 256), dim3(256), 0, stream, W, Wf);
        hipLaunchKernelGGL(moe_gate_mfma, dim3(T / BM), dim3(1024), 0, stream, X, Wf, W, out_idx, out_w);
    } else {
        hipLaunchKernelGGL(moe_gate_fallback, dim3(T / fb::BM), dim3(256), 0, stream, X, W, out_idx, out_w);
    }
}

// Round 3
// 889.941 us; speedup vs baseline: 1.0204x; 1.0204x over previous
//
#include <hip/hip_runtime.h>
#include <math.h>

typedef _Float16 half8  __attribute__((ext_vector_type(8)));
typedef _Float16 half4v __attribute__((ext_vector_type(4)));
typedef __fp16   fp16x2 __attribute__((ext_vector_type(2)));
typedef float    f32x16 __attribute__((ext_vector_type(16)));

namespace {
constexpr int H      = 4096;
constexpr int E      = 256;
constexpr int TOPK   = 8;
constexpr int NCAND  = 12;           // screened candidates per token
constexpr int BM     = 64;           // tokens per block (main kernel)
constexpr int BK     = 32;           // k per chunk
constexpr int NCHUNK = H / BK;       // 128
constexpr int SLD    = E + 4;        // 260, score row stride (floats)
constexpr float DELTA = 5e-4f;       // near-tie rescue threshold (logit units)
constexpr size_t WF_BYTES = (size_t)E * H * 2 * 2;  // 4 MB: hi+lo fp16
}

// ---------------- W pre-convert: fp32 -> fragment-ordered hi/lo fp16 --------
// Layout (halves): [nt(8)][ks(256)][hilo(2)][lane(64)][j(8)]
//   element W[e][k] (scaled by 64): nt=e>>5, ks=k>>4,
//   lane=(e&31) | (((k>>3)&1)<<5), j=k&7
__global__ void convert_w_kernel(const float* __restrict__ W,
                                 _Float16* __restrict__ Wf) {
    int t  = blockIdx.x * blockDim.x + threadIdx.x;
    int e  = t >> 10;
    int kq = t & 1023;           // k = kq*4
    float4 w4 = *(const float4*)(W + ((size_t)e << 12) + (kq << 2));
    float x0 = w4.x * 64.0f, x1 = w4.y * 64.0f, x2 = w4.z * 64.0f, x3 = w4.w * 64.0f;
    _Float16 h0 = (_Float16)x0, h1 = (_Float16)x1, h2 = (_Float16)x2, h3 = (_Float16)x3;
    _Float16 l0 = (_Float16)(x0 - (float)h0), l1 = (_Float16)(x1 - (float)h1);
    _Float16 l2 = (_Float16)(x2 - (float)h2), l3 = (_Float16)(x3 - (float)h3);
    int k    = kq << 2;
    int nt   = e >> 5;
    int ks   = k >> 4;
    int lane = (e & 31) | (((k >> 3) & 1) << 5);
    int j    = k & 7;            // 0 or 4
    size_t base = (((size_t)nt * 256 + ks) * 2) * 512 + lane * 8 + j;
    half4v hv = {h0, h1, h2, h3};
    half4v lv = {l0, l1, l2, l3};
    *(half4v*)(Wf + base)       = hv;   // hilo=0
    *(half4v*)(Wf + base + 512) = lv;   // hilo=1
}

// ---------------- main fused kernel: barrier-free split-fp16 MFMA + top8 ----
// 16 waves: mt (row half, 0..1) x wc (32-expert slice, 0..7).
// A fragments loaded DIRECTLY from global X (no LDS staging, no K-loop
// barriers), converted to hi/lo fp16 in registers. Register double-buffer
// (depth-1 prefetch).
// amdgpu_waves_per_eu(4,4): pin EXACTLY 4 waves/EU (1 block/CU, grid=256)
// so the allocator gets the full 128-VGPR budget. Round-2 post-mortem:
// __launch_bounds__(1024,4) let the compiler target 8 waves/EU -> 64 VGPR
// cap -> 27 MB of scratch spill (WRITE_SIZE) -> 651 us.
struct Pipe { half8 bh[2], bl[2]; float4 a[2][2]; };

__global__ __attribute__((amdgpu_flat_work_group_size(1024, 1024),
                          amdgpu_waves_per_eu(4, 4)))
void moe_gate_mfma(const float* __restrict__ X, const _Float16* __restrict__ Wf,
                   const float* __restrict__ Wg,
                   float* __restrict__ out_idx, float* __restrict__ out_w) {
    __shared__ float sc[BM * SLD];   // epilogue scores only (66560 B)

    const int tid  = threadIdx.x;
    const int lane = tid & 63;
    const int wave = tid >> 6;      // 0..15
    const int mt   = wave >> 3;     // row half (0..1)
    const int wc   = wave & 7;      // expert slice (0..7), 32 experts each
    const int m0   = blockIdx.x * BM;

    // A-fragment addressing for mfma_32x32x16_f16:
    //   lane holds A[row = lane&31][k = ks*16 + (lane>>5)*8 + (0..7)]
    const int arow = lane & 31;
    const int akhi = (lane >> 5) << 3;     // 0 or 8
    const float* xrow = X + (size_t)(m0 + mt * 32 + arow) * H + akhi;
    const _Float16* wbase = Wf + (size_t)wc * 256 * 2 * 512 + (size_t)lane * 8;

    f32x16 acc;
    #pragma unroll
    for (int r = 0; r < 16; ++r) acc[r] = 0.0f;

    auto load_pipe = [&](int kc, Pipe& P) {
        #pragma unroll
        for (int ks = 0; ks < 2; ++ks) {
            size_t off = (size_t)(kc * 2 + ks) * 1024;
            P.bh[ks]   = *(const half8*)(wbase + off);
            P.bl[ks]   = *(const half8*)(wbase + off + 512);
            P.a[ks][0] = *(const float4*)(xrow + kc * 32 + ks * 16);
            P.a[ks][1] = *(const float4*)(xrow + kc * 32 + ks * 16 + 4);
        }
    };
    auto compute = [&](const Pipe& P) {
        #pragma unroll
        for (int ks = 0; ks < 2; ++ks) {
            const float4 u = P.a[ks][0], v = P.a[ks][1];
            fp16x2 h0 = __builtin_amdgcn_cvt_pkrtz(u.x, u.y);
            fp16x2 h1 = __builtin_amdgcn_cvt_pkrtz(u.z, u.w);
            fp16x2 h2 = __builtin_amdgcn_cvt_pkrtz(v.x, v.y);
            fp16x2 h3 = __builtin_amdgcn_cvt_pkrtz(v.z, v.w);
            fp16x2 l0 = __builtin_amdgcn_cvt_pkrtz(u.x - (float)h0.x, u.y - (float)h0.y);
            fp16x2 l1 = __builtin_amdgcn_cvt_pkrtz(u.z - (float)h1.x, u.w - (float)h1.y);
            fp16x2 l2 = __builtin_amdgcn_cvt_pkrtz(v.x - (float)h2.x, v.y - (float)h2.y);
            fp16x2 l3 = __builtin_amdgcn_cvt_pkrtz(v.z - (float)h3.x, v.w - (float)h3.y);
            half8 ah = {(_Float16)h0.x, (_Float16)h0.y, (_Float16)h1.x, (_Float16)h1.y,
                        (_Float16)h2.x, (_Float16)h2.y, (_Float16)h3.x, (_Float16)h3.y};
            half8 al = {(_Float16)l0.x, (_Float16)l0.y, (_Float16)l1.x, (_Float16)l1.y,
                        (_Float16)l2.x, (_Float16)l2.y, (_Float16)l3.x, (_Float16)l3.y};
            acc = __builtin_amdgcn_mfma_f32_32x32x16_f16(ah, P.bh[ks], acc, 0, 0, 0);
            acc = __builtin_amdgcn_mfma_f32_32x32x16_f16(al, P.bh[ks], acc, 0, 0, 0);
            acc = __builtin_amdgcn_mfma_f32_32x32x16_f16(ah, P.bl[ks], acc, 0, 0, 0);
        }
    };

    Pipe p0, p1;
    load_pipe(0, p0);
    #pragma unroll 1
    for (int kc = 0; kc < NCHUNK; kc += 2) {
        const int k1 = kc + 1;                                // always < NCHUNK
        const int k2 = (kc + 2 < NCHUNK) ? kc + 2 : kc;       // tail-safe dup
        load_pipe(k1, p1);
        compute(p0);
        load_pipe(k2, p0);
        compute(p1);
    }

    // -------- logits -> LDS (undo the x64 W prescale) --------
    #pragma unroll
    for (int r = 0; r < 16; ++r) {
        int row = (r & 3) + 8 * (r >> 2) + 4 * (lane >> 5);
        int col = lane & 31;
        sc[(mt * 32 + row) * SLD + wc * 32 + col] = acc[r] * 0.015625f;
    }
    __syncthreads();

    // -------- top-12 screen on logits + fp64 rescue for near-ties -----------
    for (int t4 = 0; t4 < 4; ++t4) {
        const int t = wave * 4 + t4;
        float4 pv = *(const float4*)(sc + t * SLD + lane * 4);
        float p0s = pv.x, p1s = pv.y, p2s = pv.z, p3s = pv.w;

        float tv[NCAND]; int ti[NCAND];
        #pragma unroll
        for (int s = 0; s < NCAND; ++s) {
            float bv = p0s; int bi = lane * 4;
            if (p1s > bv || (p1s == bv && lane * 4 + 1 < bi)) { bv = p1s; bi = lane * 4 + 1; }
            if (p2s > bv || (p2s == bv && lane * 4 + 2 < bi)) { bv = p2s; bi = lane * 4 + 2; }
            if (p3s > bv || (p3s == bv && lane * 4 + 3 < bi)) { bv = p3s; bi = lane * 4 + 3; }
            #pragma unroll
            for (int off = 32; off > 0; off >>= 1) {
                float ov = __shfl_xor(bv, off, 64);
                int   oi = __shfl_xor(bi, off, 64);
                if (ov > bv || (ov == bv && oi < bi)) { bv = ov; bi = oi; }
            }
            tv[s] = bv; ti[s] = bi;
            if ((bi >> 2) == lane) {
                const int sl = bi & 3;
                if      (sl == 0) p0s = -3e38f;
                else if (sl == 1) p1s = -3e38f;
                else if (sl == 2) p2s = -3e38f;
                else              p3s = -3e38f;
            }
        }

        // near-tie detection among the decisive gaps (ranks 0-1 .. 8-9)
        bool rescue = false;
        #pragma unroll
        for (int g = 0; g < 9; ++g) rescue |= (tv[g] - tv[g + 1] < DELTA);

        if (rescue) {  // wave-uniform branch (tv identical across lanes)
            double dv[NCAND];
            const float* xr = X + (size_t)(m0 + t) * H;
            #pragma unroll 1
            for (int c = 0; c < NCAND; ++c) {
                const float* wrow = Wg + (size_t)ti[c] * H;
                double s_ = 0.0;
                #pragma unroll
                for (int it = 0; it < 16; ++it) {
                    float4 xa = *(const float4*)(xr + it * 256 + lane * 4);
                    float4 wa = *(const float4*)(wrow + it * 256 + lane * 4);
                    s_ += (double)xa.x * wa.x + (double)xa.y * wa.y
                        + (double)xa.z * wa.z + (double)xa.w * wa.w;
                }
                #pragma unroll
                for (int off = 32; off > 0; off >>= 1) s_ += __shfl_xor(s_, off, 64);
                dv[c] = s_;
            }
            // exact selection sort of top 8 (desc, lower index on tie)
            int si[NCAND];
            #pragma unroll
            for (int c = 0; c < NCAND; ++c) si[c] = ti[c];
            #pragma unroll
            for (int a = 0; a < TOPK; ++a) {
                int best = a;
                #pragma unroll
                for (int b = a + 1; b < NCAND; ++b) {
                    if (dv[b] > dv[best] || (dv[b] == dv[best] && si[b] < si[best])) best = b;
                }
                double tdv = dv[a]; dv[a] = dv[best]; dv[best] = tdv;
                int    tsi = si[a]; si[a] = si[best]; si[best] = tsi;
            }
            #pragma unroll
            for (int s = 0; s < TOPK; ++s) { tv[s] = (float)dv[s]; ti[s] = si[s]; }
        }

        if (lane == 0) {
            // weights = 2.5 * softmax over the top-8 logits (full-Z cancels)
            float M = tv[0];
            float e8[TOPK]; float den = 0.0f;
            #pragma unroll
            for (int s = 0; s < TOPK; ++s) { e8[s] = expf(tv[s] - M); den += e8[s]; }
            float scl = 2.5f / den;
            size_t tok = (size_t)(m0 + t);
            #pragma unroll
            for (int s = 0; s < TOPK; ++s) {
                out_idx[tok * TOPK + s] = (float)ti[s];
                out_w[tok * TOPK + s]   = e8[s] * scl;
            }
        }
    }
}

// ---------------- fallback (round-1 fp32 kernel, correctness-proven) --------
namespace fb {
constexpr int BM = 32, BK = 32;
constexpr int XS_LD = BM + 4, WS_LD = E + 4;
constexpr int LDS_FLOATS = BK * XS_LD + BK * WS_LD;
}

__global__ __launch_bounds__(256, 2)
void moe_gate_fallback(const float* __restrict__ X, const float* __restrict__ W,
                       float* __restrict__ out_idx, float* __restrict__ out_w) {
    __shared__ float lds[fb::LDS_FLOATS];
    float* xs = lds;
    float* ws = lds + fb::BK * fb::XS_LD;
    const int tid = threadIdx.x;
    const int tx = tid & 31, ty = tid >> 5;
    const int m0 = blockIdx.x * fb::BM;
    float acc[4][8];
    #pragma unroll
    for (int i = 0; i < 4; ++i)
        #pragma unroll
        for (int j = 0; j < 8; ++j) acc[i][j] = 0.0f;
    const int lr = tid >> 3, lc = (tid & 7) * 4;
    const float* xg = X + (size_t)(m0 + lr) * H + lc;
    const float* wg = W + (size_t)lr * H + lc;
    for (int kc = 0; kc < H; kc += fb::BK) {
        float4 xv = *(const float4*)(xg + kc);
        float4 wv[8];
        #pragma unroll
        for (int i = 0; i < 8; ++i) wv[i] = *(const float4*)(wg + (size_t)i * 32 * H + kc);
        __syncthreads();
        #pragma unroll
        for (int j = 0; j < 4; ++j) xs[(lc + j) * fb::XS_LD + lr] = ((const float*)&xv)[j];
        #pragma unroll
        for (int i = 0; i < 8; ++i)
            #pragma unroll
            for (int j = 0; j < 4; ++j)
                ws[(lc + j) * fb::WS_LD + i * 32 + lr] = ((const float*)&wv[i])[j];
        __syncthreads();
        #pragma unroll
        for (int kk = 0; kk < fb::BK; ++kk) {
            float4 xa = *(const float4*)(xs + kk * fb::XS_LD + ty * 4);
            float4 wb0 = *(const float4*)(ws + kk * fb::WS_LD + tx * 8);
            float4 wb1 = *(const float4*)(ws + kk * fb::WS_LD + tx * 8 + 4);
            const float xr[4] = {xa.x, xa.y, xa.z, xa.w};
            const float wr8[8] = {wb0.x, wb0.y, wb0.z, wb0.w, wb1.x, wb1.y, wb1.z, wb1.w};
            #pragma unroll
            for (int i = 0; i < 4; ++i)
                #pragma unroll
                for (int j = 0; j < 8; ++j) acc[i][j] = fmaf(xr[i], wr8[j], acc[i][j]);
        }
    }
    __syncthreads();
    float* sc = lds;
    #pragma unroll
    for (int i = 0; i < 4; ++i) {
        *(float4*)(sc + (ty * 4 + i) * fb::WS_LD + tx * 8) =
            make_float4(acc[i][0], acc[i][1], acc[i][2], acc[i][3]);
        *(float4*)(sc + (ty * 4 + i) * fb::WS_LD + tx * 8 + 4) =
            make_float4(acc[i][4], acc[i][5], acc[i][6], acc[i][7]);
    }
    __syncthreads();
    const int wave = tid >> 6, lane = tid & 63;
    for (int t8 = 0; t8 < 8; ++t8) {
        const int t = wave * 8 + t8;
        float4 pv = *(const float4*)(sc + t * fb::WS_LD + lane * 4);
        float v0 = pv.x, v1 = pv.y, v2 = pv.z, v3 = pv.w;
        float M = fmaxf(fmaxf(v0, v1), fmaxf(v2, v3));
        #pragma unroll
        for (int off = 32; off > 0; off >>= 1) M = fmaxf(M, __shfl_xor(M, off, 64));
        float p0 = expf(v0 - M), p1 = expf(v1 - M), p2 = expf(v2 - M), p3 = expf(v3 - M);
        float z = p0 + p1 + p2 + p3;
        #pragma unroll
        for (int off = 32; off > 0; off >>= 1) z += __shfl_xor(z, off, 64);
        p0 /= z; p1 /= z; p2 /= z; p3 /= z;
        float tv[TOPK]; int ti[TOPK];
        #pragma unroll
        for (int s = 0; s < TOPK; ++s) {
            float bv = p0; int bi = lane * 4;
            if (p1 > bv || (p1 == bv && lane * 4 + 1 < bi)) { bv = p1; bi = lane * 4 + 1; }
            if (p2 > bv || (p2 == bv && lane * 4 + 2 < bi)) { bv = p2; bi = lane * 4 + 2; }
            if (p3 > bv || (p3 == bv && lane * 4 + 3 < bi)) { bv = p3; bi = lane * 4 + 3; }
            #pragma unroll
            for (int off = 32; off > 0; off >>= 1) {
                float ov = __shfl_xor(bv, off, 64);
                int   oi = __shfl_xor(bi, off, 64);
                if (ov > bv || (ov == bv && oi < bi)) { bv = ov; bi = oi; }
            }
            tv[s] = bv; ti[s] = bi;
            if ((bi >> 2) == lane) {
                const int sl = bi & 3;
                if      (sl == 0) p0 = -1.0f;
                else if (sl == 1) p1 = -1.0f;
                else if (sl == 2) p2 = -1.0f;
                else              p3 = -1.0f;
            }
        }
        if (lane == 0) {
            float den = tv[0] + tv[1] + tv[2] + tv[3] + tv[4] + tv[5] + tv[6] + tv[7] + 1e-20f;
            float scl = 2.5f / den;
            size_t tok = (size_t)(m0 + t);
            #pragma unroll
            for (int s = 0; s < TOPK; ++s) {
                out_idx[tok * TOPK + s] = (float)ti[s];
                out_w[tok * TOPK + s]   = tv[s] * scl;
            }
        }
    }
}

extern "C" void kernel_launch(void* const* d_in, const int* in_sizes, int n_in,
                              void* d_out, int out_size, void* d_ws, size_t ws_size,
                              hipStream_t stream) {
    const float* X = (const float*)d_in[0];
    const float* W = (const float*)d_in[1];
    float* out = (float*)d_out;
    const int T = in_sizes[0] / H;
    float* out_idx = out;
    float* out_w   = out + (size_t)T * TOPK;

    if (ws_size >= WF_BYTES && (T % BM) == 0) {
        _Float16* Wf = (_Float16*)d_ws;
        hipLaunchKernelGGL(convert_w_kernel, dim3((E * (H / 4)) / 256), dim3(256), 0, stream, W, Wf);
        hipLaunchKernelGGL(moe_gate_mfma, dim3(T / BM), dim3(1024), 0, stream, X, Wf, W, out_idx, out_w);
    } else {
        hipLaunchKernelGGL(moe_gate_fallback, dim3(T / fb::BM), dim3(256), 0, stream, X, W, out_idx, out_w);
    }
}

// Round 4
// 750.918 us; speedup vs baseline: 1.2093x; 1.1851x over previous
//
#include <hip/hip_runtime.h>
#include <math.h>

typedef _Float16 half8  __attribute__((ext_vector_type(8)));
typedef _Float16 half4v __attribute__((ext_vector_type(4)));
typedef float    f32x16 __attribute__((ext_vector_type(16)));

namespace {
constexpr int H      = 4096;
constexpr int E      = 256;
constexpr int TOPK   = 8;
constexpr int NCAND  = 12;           // screened candidates per token
constexpr int BM     = 32;           // tokens per block (main kernel)
constexpr int BK     = 32;           // k per chunk
constexpr int NCHUNK = H / BK;       // 128
constexpr int SLD    = E + 4;        // 260, score row stride (floats)
constexpr float DELTA = 5e-4f;       // near-tie rescue threshold (logit units)
constexpr size_t WF_BYTES = (size_t)E * H * 2 * 2;  // 4 MB: hi+lo fp16
constexpr int SMEM_BYTES = BM * SLD * 4;  // 33280 (A dbuf = 8 KB aliases inside)
}

// ---------------- W pre-convert: fp32 -> fragment-ordered hi/lo fp16 --------
// Layout (halves): [grp(8)][ks(256)][hilo(2)][lane(64)][j(8)]
//   element W[e][k] (scaled by 64): grp=e>>5, ks=k>>4,
//   lane=(e&31) | (((k>>3)&1)<<5), j=k&7
__global__ void convert_w_kernel(const float* __restrict__ W,
                                 _Float16* __restrict__ Wf) {
    int t  = blockIdx.x * blockDim.x + threadIdx.x;
    int e  = t >> 10;
    int kq = t & 1023;           // k = kq*4
    float4 w4 = *(const float4*)(W + ((size_t)e << 12) + (kq << 2));
    float x0 = w4.x * 64.0f, x1 = w4.y * 64.0f, x2 = w4.z * 64.0f, x3 = w4.w * 64.0f;
    _Float16 h0 = (_Float16)x0, h1 = (_Float16)x1, h2 = (_Float16)x2, h3 = (_Float16)x3;
    _Float16 l0 = (_Float16)(x0 - (float)h0), l1 = (_Float16)(x1 - (float)h1);
    _Float16 l2 = (_Float16)(x2 - (float)h2), l3 = (_Float16)(x3 - (float)h3);
    int k    = kq << 2;
    int grp  = e >> 5;
    int ks   = k >> 4;
    int lane = (e & 31) | (((k >> 3) & 1) << 5);
    int j    = k & 7;            // 0 or 4
    size_t base = (((size_t)grp * 256 + ks) * 2) * 512 + lane * 8 + j;
    half4v hv = {h0, h1, h2, h3};
    half4v lv = {l0, l1, l2, l3};
    *(half4v*)(Wf + base)       = hv;   // hilo=0
    *(half4v*)(Wf + base + 512) = lv;   // hilo=1
}

// ---------------- main fused kernel: split-fp16 MFMA GEMM + top8 ------------
// BM=32: grid = T/32 = 512 blocks = 2 blocks/CU (round-0's BM=64 gave exactly
// 1 block/CU -> 2 waves/SIMD -> unhidden barrier drains, 483 us). Two
// independent blocks per CU overlap each other's barrier/drain stalls.
// 8 waves, each owns one 32x32 tile: all 32 tokens x 32 experts (wc).
struct BF { half8 h[2]; half8 l[2]; };  // [k_step]

__global__ __launch_bounds__(512, 2)
void moe_gate_mfma(const float* __restrict__ X, const _Float16* __restrict__ Wf,
                   const float* __restrict__ Wg,
                   float* __restrict__ out_idx, float* __restrict__ out_w) {
    __shared__ __align__(16) char smem[SMEM_BYTES];
    _Float16* Abuf = (_Float16*)smem;       // 2 buffers x 2048 halves (8 KB)
    float*    sc   = (float*)smem;          // epilogue scores [32][SLD]

    const int tid  = threadIdx.x;
    const int lane = tid & 63;
    const int wave = tid >> 6;      // 0..7
    const int wc   = wave;          // expert slice, 32 experts each
    const int m0   = blockIdx.x * BM;

    // staging: tid<256 covers the 32x32 fp32 X tile (one float4 each)
    const bool active = tid < 256;
    const int m_s  = (tid >> 3) & 31;   // 0..31 (tid>=256 duplicates, unused)
    const int kq_s = tid & 7;           // 0..7, k = kq_s*4
    const int ks_s = kq_s >> 2;                              // k_step 0/1
    const int ln_s = m_s | (((kq_s >> 1) & 1) << 5);         // frag lane
    const int j_s  = (kq_s & 1) * 4;                         // frag elem 0/4
    const int dst_s = ks_s * 1024 + ln_s * 8 + j_s;
    const float* xgp = X + (size_t)(m0 + m_s) * H + kq_s * 4;

    f32x16 acc;
    #pragma unroll
    for (int r = 0; r < 16; ++r) acc[r] = 0.0f;

    auto load_b = [&](int kc, BF& b) {
        #pragma unroll
        for (int ks = 0; ks < 2; ++ks) {
            size_t base = (((size_t)wc * 256 + (kc * 2 + ks)) * 2) * 512 + lane * 8;
            b.h[ks] = *(const half8*)(Wf + base);
            b.l[ks] = *(const half8*)(Wf + base + 512);
        }
    };
    auto stage = [&](int bufIdx, float4 xv) {
        if (!active) return;
        _Float16* buf = Abuf + bufIdx * 2048;
        float x0 = xv.x, x1 = xv.y, x2 = xv.z, x3 = xv.w;
        _Float16 h0 = (_Float16)x0, h1 = (_Float16)x1, h2 = (_Float16)x2, h3 = (_Float16)x3;
        _Float16 l0 = (_Float16)(x0 - (float)h0), l1 = (_Float16)(x1 - (float)h1);
        _Float16 l2 = (_Float16)(x2 - (float)h2), l3 = (_Float16)(x3 - (float)h3);
        half4v hv = {h0, h1, h2, h3};
        half4v lv = {l0, l1, l2, l3};
        *(half4v*)(buf + dst_s)       = hv;
        *(half4v*)(buf + dst_s + 512) = lv;
    };
    auto compute = [&](int bufIdx, const BF& b) {
        const _Float16* buf = Abuf + bufIdx * 2048;
        #pragma unroll
        for (int ks = 0; ks < 2; ++ks) {
            const _Float16* p = buf + ks * 1024 + lane * 8;
            half8 a_hi = *(const half8*)p;
            half8 a_lo = *(const half8*)(p + 512);
            acc = __builtin_amdgcn_mfma_f32_32x32x16_f16(a_hi, b.h[ks], acc, 0, 0, 0);
            acc = __builtin_amdgcn_mfma_f32_32x32x16_f16(a_lo, b.h[ks], acc, 0, 0, 0);
            acc = __builtin_amdgcn_mfma_f32_32x32x16_f16(a_hi, b.l[ks], acc, 0, 0, 0);
        }
    };

    // prologue
    BF bcur;
    load_b(0, bcur);
    float4 xv = *(const float4*)(xgp);
    stage(0, xv);
    __syncthreads();
    float4 xnxt = *(const float4*)(xgp + BK);

    for (int kc = 0; kc < NCHUNK; ++kc) {
        BF bnxt;
        float4 xfar = make_float4(0.f, 0.f, 0.f, 0.f);
        if (kc + 1 < NCHUNK) load_b(kc + 1, bnxt);
        if (kc + 2 < NCHUNK) xfar = *(const float4*)(xgp + (size_t)(kc + 2) * BK);
        compute(kc & 1, bcur);
        if (kc + 1 < NCHUNK) {
            stage((kc + 1) & 1, xnxt);
            __syncthreads();
        }
        bcur = bnxt;
        xnxt = xfar;
    }

    // -------- logits -> LDS (undo the x64 W prescale) --------
    __syncthreads();
    #pragma unroll
    for (int r = 0; r < 16; ++r) {
        int row = (r & 3) + 8 * (r >> 2) + 4 * (lane >> 5);
        int col = lane & 31;
        sc[row * SLD + wc * 32 + col] = acc[r] * 0.015625f;
    }
    __syncthreads();

    // -------- top-12 screen on logits + fp64 rescue for near-ties -----------
    for (int t4 = 0; t4 < 4; ++t4) {
        const int t = wave * 4 + t4;
        float4 pv = *(const float4*)(sc + t * SLD + lane * 4);
        float p0 = pv.x, p1 = pv.y, p2 = pv.z, p3 = pv.w;

        float tv[NCAND]; int ti[NCAND];
        #pragma unroll
        for (int s = 0; s < NCAND; ++s) {
            float bv = p0; int bi = lane * 4;
            if (p1 > bv || (p1 == bv && lane * 4 + 1 < bi)) { bv = p1; bi = lane * 4 + 1; }
            if (p2 > bv || (p2 == bv && lane * 4 + 2 < bi)) { bv = p2; bi = lane * 4 + 2; }
            if (p3 > bv || (p3 == bv && lane * 4 + 3 < bi)) { bv = p3; bi = lane * 4 + 3; }
            #pragma unroll
            for (int off = 32; off > 0; off >>= 1) {
                float ov = __shfl_xor(bv, off, 64);
                int   oi = __shfl_xor(bi, off, 64);
                if (ov > bv || (ov == bv && oi < bi)) { bv = ov; bi = oi; }
            }
            tv[s] = bv; ti[s] = bi;
            if ((bi >> 2) == lane) {
                const int sl = bi & 3;
                if      (sl == 0) p0 = -3e38f;
                else if (sl == 1) p1 = -3e38f;
                else if (sl == 2) p2 = -3e38f;
                else              p3 = -3e38f;
            }
        }

        // near-tie detection among the decisive gaps (ranks 0-1 .. 8-9)
        bool rescue = false;
        #pragma unroll
        for (int g = 0; g < 9; ++g) rescue |= (tv[g] - tv[g + 1] < DELTA);

        if (rescue) {  // wave-uniform branch (tv identical across lanes)
            double dv[NCAND];
            const float* xr = X + (size_t)(m0 + t) * H;
            #pragma unroll 1
            for (int c = 0; c < NCAND; ++c) {
                const float* wrow = Wg + (size_t)ti[c] * H;
                double s_ = 0.0;
                #pragma unroll
                for (int it = 0; it < 16; ++it) {
                    float4 xa = *(const float4*)(xr + it * 256 + lane * 4);
                    float4 wa = *(const float4*)(wrow + it * 256 + lane * 4);
                    s_ += (double)xa.x * wa.x + (double)xa.y * wa.y
                        + (double)xa.z * wa.z + (double)xa.w * wa.w;
                }
                #pragma unroll
                for (int off = 32; off > 0; off >>= 1) s_ += __shfl_xor(s_, off, 64);
                dv[c] = s_;
            }
            // exact selection sort of top 8 (desc, lower index on tie)
            int si[NCAND];
            #pragma unroll
            for (int c = 0; c < NCAND; ++c) si[c] = ti[c];
            #pragma unroll
            for (int a = 0; a < TOPK; ++a) {
                int best = a;
                #pragma unroll
                for (int b = a + 1; b < NCAND; ++b) {
                    if (dv[b] > dv[best] || (dv[b] == dv[best] && si[b] < si[best])) best = b;
                }
                double tdv = dv[a]; dv[a] = dv[best]; dv[best] = tdv;
                int    tsi = si[a]; si[a] = si[best]; si[best] = tsi;
            }
            #pragma unroll
            for (int s = 0; s < TOPK; ++s) { tv[s] = (float)dv[s]; ti[s] = si[s]; }
        }

        if (lane == 0) {
            // weights = 2.5 * softmax over the top-8 logits (full-Z cancels)
            float M = tv[0];
            float e8[TOPK]; float den = 0.0f;
            #pragma unroll
            for (int s = 0; s < TOPK; ++s) { e8[s] = expf(tv[s] - M); den += e8[s]; }
            float scl = 2.5f / den;
            size_t tok = (size_t)(m0 + t);
            #pragma unroll
            for (int s = 0; s < TOPK; ++s) {
                out_idx[tok * TOPK + s] = (float)ti[s];
                out_w[tok * TOPK + s]   = e8[s] * scl;
            }
        }
    }
}

// ---------------- fallback (round-1 fp32 kernel, correctness-proven) --------
namespace fb {
constexpr int BM = 32, BK = 32;
constexpr int XS_LD = BM + 4, WS_LD = E + 4;
constexpr int LDS_FLOATS = BK * XS_LD + BK * WS_LD;
}

__global__ __launch_bounds__(256, 2)
void moe_gate_fallback(const float* __restrict__ X, const float* __restrict__ W,
                       float* __restrict__ out_idx, float* __restrict__ out_w) {
    __shared__ float lds[fb::LDS_FLOATS];
    float* xs = lds;
    float* ws = lds + fb::BK * fb::XS_LD;
    const int tid = threadIdx.x;
    const int tx = tid & 31, ty = tid >> 5;
    const int m0 = blockIdx.x * fb::BM;
    float acc[4][8];
    #pragma unroll
    for (int i = 0; i < 4; ++i)
        #pragma unroll
        for (int j = 0; j < 8; ++j) acc[i][j] = 0.0f;
    const int lr = tid >> 3, lc = (tid & 7) * 4;
    const float* xg = X + (size_t)(m0 + lr) * H + lc;
    const float* wg = W + (size_t)lr * H + lc;
    for (int kc = 0; kc < H; kc += fb::BK) {
        float4 xv = *(const float4*)(xg + kc);
        float4 wv[8];
        #pragma unroll
        for (int i = 0; i < 8; ++i) wv[i] = *(const float4*)(wg + (size_t)i * 32 * H + kc);
        __syncthreads();
        #pragma unroll
        for (int j = 0; j < 4; ++j) xs[(lc + j) * fb::XS_LD + lr] = ((const float*)&xv)[j];
        #pragma unroll
        for (int i = 0; i < 8; ++i)
            #pragma unroll
            for (int j = 0; j < 4; ++j)
                ws[(lc + j) * fb::WS_LD + i * 32 + lr] = ((const float*)&wv[i])[j];
        __syncthreads();
        #pragma unroll
        for (int kk = 0; kk < fb::BK; ++kk) {
            float4 xa = *(const float4*)(xs + kk * fb::XS_LD + ty * 4);
            float4 wb0 = *(const float4*)(ws + kk * fb::WS_LD + tx * 8);
            float4 wb1 = *(const float4*)(ws + kk * fb::WS_LD + tx * 8 + 4);
            const float xr[4] = {xa.x, xa.y, xa.z, xa.w};
            const float wr8[8] = {wb0.x, wb0.y, wb0.z, wb0.w, wb1.x, wb1.y, wb1.z, wb1.w};
            #pragma unroll
            for (int i = 0; i < 4; ++i)
                #pragma unroll
                for (int j = 0; j < 8; ++j) acc[i][j] = fmaf(xr[i], wr8[j], acc[i][j]);
        }
    }
    __syncthreads();
    float* sc = lds;
    #pragma unroll
    for (int i = 0; i < 4; ++i) {
        *(float4*)(sc + (ty * 4 + i) * fb::WS_LD + tx * 8) =
            make_float4(acc[i][0], acc[i][1], acc[i][2], acc[i][3]);
        *(float4*)(sc + (ty * 4 + i) * fb::WS_LD + tx * 8 + 4) =
            make_float4(acc[i][4], acc[i][5], acc[i][6], acc[i][7]);
    }
    __syncthreads();
    const int wave = tid >> 6, lane = tid & 63;
    for (int t8 = 0; t8 < 8; ++t8) {
        const int t = wave * 8 + t8;
        float4 pv = *(const float4*)(sc + t * fb::WS_LD + lane * 4);
        float v0 = pv.x, v1 = pv.y, v2 = pv.z, v3 = pv.w;
        float M = fmaxf(fmaxf(v0, v1), fmaxf(v2, v3));
        #pragma unroll
        for (int off = 32; off > 0; off >>= 1) M = fmaxf(M, __shfl_xor(M, off, 64));
        float p0 = expf(v0 - M), p1 = expf(v1 - M), p2 = expf(v2 - M), p3 = expf(v3 - M);
        float z = p0 + p1 + p2 + p3;
        #pragma unroll
        for (int off = 32; off > 0; off >>= 1) z += __shfl_xor(z, off, 64);
        p0 /= z; p1 /= z; p2 /= z; p3 /= z;
        float tv[TOPK]; int ti[TOPK];
        #pragma unroll
        for (int s = 0; s < TOPK; ++s) {
            float bv = p0; int bi = lane * 4;
            if (p1 > bv || (p1 == bv && lane * 4 + 1 < bi)) { bv = p1; bi = lane * 4 + 1; }
            if (p2 > bv || (p2 == bv && lane * 4 + 2 < bi)) { bv = p2; bi = lane * 4 + 2; }
            if (p3 > bv || (p3 == bv && lane * 4 + 3 < bi)) { bv = p3; bi = lane * 4 + 3; }
            #pragma unroll
            for (int off = 32; off > 0; off >>= 1) {
                float ov = __shfl_xor(bv, off, 64);
                int   oi = __shfl_xor(bi, off, 64);
                if (ov > bv || (ov == bv && oi < bi)) { bv = ov; bi = oi; }
            }
            tv[s] = bv; ti[s] = bi;
            if ((bi >> 2) == lane) {
                const int sl = bi & 3;
                if      (sl == 0) p0 = -1.0f;
                else if (sl == 1) p1 = -1.0f;
                else if (sl == 2) p2 = -1.0f;
                else              p3 = -1.0f;
            }
        }
        if (lane == 0) {
            float den = tv[0] + tv[1] + tv[2] + tv[3] + tv[4] + tv[5] + tv[6] + tv[7] + 1e-20f;
            float scl = 2.5f / den;
            size_t tok = (size_t)(m0 + t);
            #pragma unroll
            for (int s = 0; s < TOPK; ++s) {
                out_idx[tok * TOPK + s] = (float)ti[s];
                out_w[tok * TOPK + s]   = tv[s] * scl;
            }
        }
    }
}

extern "C" void kernel_launch(void* const* d_in, const int* in_sizes, int n_in,
                              void* d_out, int out_size, void* d_ws, size_t ws_size,
                              hipStream_t stream) {
    const float* X = (const float*)d_in[0];
    const float* W = (const float*)d_in[1];
    float* out = (float*)d_out;
    const int T = in_sizes[0] / H;
    float* out_idx = out;
    float* out_w   = out + (size_t)T * TOPK;

    if (ws_size >= WF_BYTES && (T % BM) == 0) {
        _Float16* Wf = (_Float16*)d_ws;
        hipLaunchKernelGGL(convert_w_kernel, dim3((E * (H / 4)) / 256), dim3(256), 0, stream, W, Wf);
        hipLaunchKernelGGL(moe_gate_mfma, dim3(T / BM), dim3(512), 0, stream, X, Wf, W, out_idx, out_w);
    } else {
        hipLaunchKernelGGL(moe_gate_fallback, dim3(T / fb::BM), dim3(256), 0, stream, X, W, out_idx, out_w);
    }
}